// Round 1
// 205.298 us; speedup vs baseline: 1.0239x; 1.0239x over previous
//
#include <hip/hip_runtime.h>

#define N_TOT 65536
#define C_DIM 128
#define K_CB  1024
#define BN 64
#define BT 64
#define NTILE (K_CB / BT)
#define NROW_B 4
#define NBLK_B (N_TOT / NROW_B)

typedef __attribute__((ext_vector_type(8))) short bf16x8;   // 8 bf16 = 4 VGPR
typedef __attribute__((ext_vector_type(4))) float f32x4;

__device__ __forceinline__ ushort f2bf_rne(float f) {
  unsigned u = __float_as_uint(f);
  return (ushort)((u + 0x7FFFu + ((u >> 16) & 1u)) >> 16);
}

// ---------------------------------------------------------------------------
// cb_sq[k] = fl32( fp64 sum c^2 ) — one wave per code row. (frozen)
// ---------------------------------------------------------------------------
__global__ __launch_bounds__(256) void cbsq_kernel(const float* __restrict__ cb,
                                                   float* __restrict__ out) {
  int w = threadIdx.x >> 6, lane = threadIdx.x & 63;
  int r = blockIdx.x * 4 + w;
  float2 v = reinterpret_cast<const float2*>(cb + (size_t)r * C_DIM)[lane];
  double s = (double)v.x * (double)v.x + (double)v.y * (double)v.y;
#pragma unroll
  for (int off = 32; off >= 1; off >>= 1) s += __shfl_xor(s, off, 64);
  if (lane == 0) out[r] = (float)s;
}

// ---------------------------------------------------------------------------
// Codebook -> bf16 plane (RNE). (frozen)
// ---------------------------------------------------------------------------
__global__ __launch_bounds__(256) void cbconv_kernel(const float* __restrict__ cb,
                                                     ushort* __restrict__ cbh) {
  int gid = blockIdx.x * 256 + threadIdx.x;   // 0..32767 float4s
  float4 v = reinterpret_cast<const float4*>(cb)[gid];
  ushort4 h;
  h.x = f2bf_rne(v.x); h.y = f2bf_rne(v.y);
  h.z = f2bf_rne(v.z); h.w = f2bf_rne(v.w);
  reinterpret_cast<ushort4*>(cbh)[gid] = h;
}

// ---------------------------------------------------------------------------
// MFMA filter, barrier-free K-loop, SOFTWARE-PIPELINED (R0 this session):
//  - A-frags (z) hoisted to regs once (8 x bf16x8); zhS LDS dead after.
//  - B-frags + cbsq for tile t+1 prefetched into a second register buffer
//    (bA/bB ping-pong, static names — no runtime-indexed arrays) while tile
//    t's MFMA + top-3 VALU runs. The compiler's vmcnt wait then lands a full
//    compute phase (~350 cyc) after issue, covering L2 latency (~200-300 cy)
//    that previously serialized every tile (MfmaUtil 7.8%, VALUBusy 20.6%).
//  - cbsq prefetch is the RAW load; +192.0f deferred to compute so no
//    dependent ALU forces an early waitcnt at the load site.
//  - key' = (cbsq[k]+192) - 2*dot  in [183,201] -> positive-float bits are
//    uint-monotone; packed = (bits & ~1023) | code -> top-3 via v_min/max_u32,
//    no index registers. Truncation 0.0156 << per-row gaps; top-8 rescued.
//  - pool stride 97 words (96 = 0 mod 32 banks would 64-way-conflict scans).
// ---------------------------------------------------------------------------
__global__ __launch_bounds__(256, 3) void dist_mfma_kernel(
    const float* __restrict__ ze, const ushort* __restrict__ cbh,
    const float* __restrict__ cbsq, ushort* __restrict__ cand) {
  __shared__ __align__(16) char smem[24832];              // max(z 16384, pool 24832)
  ushort* zhS = reinterpret_cast<ushort*>(smem);          // [64][128] xor-swizzled
  unsigned* pool = reinterpret_cast<unsigned*>(smem);     // [64][97]

  const int tid = threadIdx.x;
  const int w = tid >> 6, lane = tid & 63;
  const int mh = w & 1, nh = w >> 1;
  const int c16 = lane & 15, quad = lane >> 4;
  const int rowbase = blockIdx.x * BN;

  // Stage z tile -> bf16 LDS (one time).
#pragma unroll
  for (int p = 0; p < 4; ++p) {
    int fid = p * 256 + tid;
    int row = fid >> 4, c8 = fid & 15;
    float4 a = reinterpret_cast<const float4*>(ze)[(size_t)(rowbase + row) * 32 + c8 * 2];
    float4 b = reinterpret_cast<const float4*>(ze)[(size_t)(rowbase + row) * 32 + c8 * 2 + 1];
    ushort h[8] = {f2bf_rne(a.x), f2bf_rne(a.y), f2bf_rne(a.z), f2bf_rne(a.w),
                   f2bf_rne(b.x), f2bf_rne(b.y), f2bf_rne(b.z), f2bf_rne(b.w)};
    *reinterpret_cast<uint4*>(&zhS[row * 128 + ((c8 ^ (row & 7)) * 8)]) =
        *reinterpret_cast<const uint4*>(h);
  }
  __syncthreads();

  // Hoist A-frags: afrag[m2][ks], row = mh*32+m2*16+c16, k = ks*32+quad*8.
  const int xk = c16 & 7;
  bf16x8 afrag[2][4];
#pragma unroll
  for (int m2 = 0; m2 < 2; ++m2) {
    int r = (mh * 32 + m2 * 16 + c16) * 128;
#pragma unroll
    for (int ks = 0; ks < 4; ++ks)
      afrag[m2][ks] = *reinterpret_cast<const bf16x8*>(&zhS[r + ((ks * 4 + quad) ^ xk) * 8]);
  }
  __syncthreads();   // zhS dead; pool aliasing safe

  unsigned t3[8][3];
#pragma unroll
  for (int s = 0; s < 8; ++s) { t3[s][0] = 0xFFFFFFFFu; t3[s][1] = 0xFFFFFFFFu; t3[s][2] = 0xFFFFFFFFu; }

  // Per-lane B base: row (nh*32 + c16), elem quad*8.
  const ushort* bbase = cbh + (size_t)(nh * 32 + c16) * 128 + quad * 8;
  const int cbase = nh * 32 + c16;

  bf16x8 bA[2][4], bB[2][4];
  float csA[2], csB[2];

  auto LOADB = [&](bf16x8 (&B)[2][4], float (&CS)[2], int t) {
#pragma unroll
    for (int n2 = 0; n2 < 2; ++n2) {
#pragma unroll
      for (int ks = 0; ks < 4; ++ks)
        B[n2][ks] = *reinterpret_cast<const bf16x8*>(bbase + t * 8192 + n2 * 2048 + ks * 32);
      CS[n2] = cbsq[t * BT + cbase + n2 * 16];   // raw; +192 deferred to compute
    }
  };

  auto COMPUTE = [&](const bf16x8 (&B)[2][4], const float (&CS)[2], int t) {
    f32x4 acc[2][2];
#pragma unroll
    for (int m2 = 0; m2 < 2; ++m2)
#pragma unroll
      for (int n2 = 0; n2 < 2; ++n2) acc[m2][n2] = (f32x4){0.f, 0.f, 0.f, 0.f};

#pragma unroll
    for (int ks = 0; ks < 4; ++ks)
#pragma unroll
      for (int m2 = 0; m2 < 2; ++m2)
#pragma unroll
        for (int n2 = 0; n2 < 2; ++n2)
          acc[m2][n2] = __builtin_amdgcn_mfma_f32_16x16x32_bf16(afrag[m2][ks], B[n2][ks], acc[m2][n2], 0, 0, 0);

    // keys + packed top-3. D layout: col=lane&15, row=quad*4+reg (m89).
#pragma unroll
    for (int n2 = 0; n2 < 2; ++n2) {
      int code = t * BT + cbase + n2 * 16;
      float csb = CS[n2] + 192.0f;
#pragma unroll
      for (int m2 = 0; m2 < 2; ++m2)
#pragma unroll
        for (int reg = 0; reg < 4; ++reg) {
          float kf = fmaf(-2.f, acc[m2][n2][reg], csb);
          unsigned pk = (__float_as_uint(kf) & 0xFFFFFC00u) | (unsigned)code;
          int s = m2 * 4 + reg;
          unsigned c1 = min(t3[s][0], pk), h1 = max(t3[s][0], pk);
          unsigned c2 = min(t3[s][1], h1), h2 = max(t3[s][1], h1);
          unsigned c3 = min(t3[s][2], h2);
          t3[s][0] = c1; t3[s][1] = c2; t3[s][2] = c3;
        }
    }
  };

  // 1-deep pipelined K-loop: tiles processed in order 0..15; loads for tile
  // t+1 are in flight across tile t's MFMA + sort.
  LOADB(bA, csA, 0);
#pragma unroll 1
  for (int t = 0; t < NTILE - 2; t += 2) {
    LOADB(bB, csB, t + 1);
    COMPUTE(bA, csA, t);
    LOADB(bA, csA, t + 2);
    COMPUTE(bB, csB, t + 1);
  }
  LOADB(bB, csB, NTILE - 1);
  COMPUTE(bA, csA, NTILE - 2);
  COMPUTE(bB, csB, NTILE - 1);

  // Pool: 32 (nh,c16) groups x top-3 = 96 packed keys per row.
#pragma unroll
  for (int s = 0; s < 8; ++s) {
    int row = mh * 32 + (s >> 2) * 16 + quad * 4 + (s & 3);
    int col = (nh * 16 + c16) * 3;
    pool[row * 97 + col] = t3[s][0];
    pool[row * 97 + col + 1] = t3[s][1];
    pool[row * 97 + col + 2] = t3[s][2];
  }
  __syncthreads();
  if (tid < BN) {
    unsigned k[8];
#pragma unroll
    for (int q = 0; q < 8; ++q) k[q] = 0xFFFFFFFFu;
    for (int p = 0; p < 96; ++p) {
      unsigned v = pool[tid * 97 + p];
      if (v < k[7]) {
        k[7] = v;
#pragma unroll
        for (int q = 7; q > 0; --q)
          if (k[q] < k[q - 1]) { unsigned tk = k[q]; k[q] = k[q - 1]; k[q - 1] = tk; }
      }
    }
    uint4 cw;
    cw.x = (k[0] & 1023u) | ((k[1] & 1023u) << 16);
    cw.y = (k[2] & 1023u) | ((k[3] & 1023u) << 16);
    cw.z = (k[4] & 1023u) | ((k[5] & 1023u) << 16);
    cw.w = (k[6] & 1023u) | ((k[7] & 1023u) << 16);
    reinterpret_cast<uint4*>(cand)[rowbase + tid] = cw;
  }
}

// ---------------------------------------------------------------------------
// Rescore (R3/R7-verified, UNTOUCHED): np fp32 key replication
//   key = fl32( fl32( zs - fl32(2*cross_fp64) ) + cb_sq32 ), tie -> low idx.
// ---------------------------------------------------------------------------
__global__ __launch_bounds__(256) void rescore_kernel(
    const float* __restrict__ ze, const float* __restrict__ cb,
    const float* __restrict__ cbsq, const ushort* __restrict__ cand,
    float* __restrict__ zq, float* __restrict__ idx_f,
    double* __restrict__ partial) {
  int w = threadIdx.x >> 6, lane = threadIdx.x & 63;
  int row = blockIdx.x * NROW_B + w;
  int g = lane >> 3, e = lane & 7;
  int myc = cand[(size_t)row * 8 + g];

  float2 z2 = reinterpret_cast<const float2*>(ze)[(size_t)row * 64 + lane];
  double zsum = (double)z2.x * (double)z2.x + (double)z2.y * (double)z2.y;
#pragma unroll
  for (int off = 32; off >= 1; off >>= 1) zsum += __shfl_xor(zsum, off, 64);
  float zs = (float)zsum;

  const float4* zrow4 = reinterpret_cast<const float4*>(ze + (size_t)row * C_DIM);
  const float4* crow4 = reinterpret_cast<const float4*>(cb + (size_t)myc * C_DIM);
  double p = 0.0;
#pragma unroll
  for (int q = 0; q < 4; ++q) {
    float4 zz = zrow4[e * 4 + q];
    float4 cc = crow4[e * 4 + q];
    p += (double)zz.x * (double)cc.x + (double)zz.y * (double)cc.y +
         (double)zz.z * (double)cc.z + (double)zz.w * (double)cc.w;
  }
  p += __shfl_xor(p, 1, 64);
  p += __shfl_xor(p, 2, 64);
  p += __shfl_xor(p, 4, 64);

  float tt = (float)(2.0 * p);
  float u = zs - tt;
  float d = u + cbsq[myc];

  float best = 3.4e38f;
  int bidx = K_CB + 1;
#pragma unroll
  for (int gg = 0; gg < 8; ++gg) {
    float dg = __shfl(d, gg * 8, 64);
    int ig = __shfl(myc, gg * 8, 64);
    if (dg < best || (dg == best && ig < bidx)) { best = dg; bidx = ig; }
  }

  float2 c2 = reinterpret_cast<const float2*>(cb)[(size_t)bidx * 64 + lane];
  reinterpret_cast<float2*>(zq)[(size_t)row * 64 + lane] = c2;

  double dx = (double)z2.x - (double)c2.x;
  double dy = (double)z2.y - (double)c2.y;
  double l = dx * dx + dy * dy;
#pragma unroll
  for (int off = 32; off >= 1; off >>= 1) l += __shfl_xor(l, off, 64);

  __shared__ double sh[NROW_B];
  if (lane == 0) { idx_f[row] = (float)bidx; sh[w] = l; }
  __syncthreads();
  if (threadIdx.x == 0) partial[blockIdx.x] = sh[0] + sh[1] + sh[2] + sh[3];
}

__global__ __launch_bounds__(256) void finalize_kernel(
    const double* __restrict__ partial, float* __restrict__ out_loss) {
  double s = 0.0;
  for (int i = threadIdx.x; i < NBLK_B; i += 256) s += partial[i];
#pragma unroll
  for (int off = 32; off >= 1; off >>= 1) s += __shfl_down(s, off, 64);
  __shared__ double sh[4];
  int wv = threadIdx.x >> 6, lane = threadIdx.x & 63;
  if (lane == 0) sh[wv] = s;
  __syncthreads();
  if (threadIdx.x == 0) {
    double tot = sh[0] + sh[1] + sh[2] + sh[3];
    double mse = tot / (double)((size_t)N_TOT * C_DIM);
    *out_loss = (float)(1.75 * mse);  // 0.75*q_latent + e_latent, both == mse
  }
}

// ---------------------------------------------------------------------------
extern "C" void kernel_launch(void* const* d_in, const int* in_sizes, int n_in,
                              void* d_out, int out_size, void* d_ws, size_t ws_size,
                              hipStream_t stream) {
  const float* ze = (const float*)d_in[0];
  const float* cb = (const float*)d_in[1];

  float* out = (float*)d_out;
  float* zq = out;                                   // [N*C]
  float* out_loss = out + (size_t)N_TOT * C_DIM;     // [1]
  float* idx_f = out_loss + 1;                       // [N]

  float* cbsq = (float*)d_ws;                             // 4 KB @0
  ushort* cbh = (ushort*)((char*)d_ws + 8192);            // 256 KB
  ushort* cand = (ushort*)((char*)d_ws + 270336);         // 1 MB
  double* partial = (double*)((char*)d_ws + 1318912);     // 128 KB

  cbsq_kernel<<<K_CB / 4, 256, 0, stream>>>(cb, cbsq);
  cbconv_kernel<<<K_CB * C_DIM / 4 / 256, 256, 0, stream>>>(cb, cbh);
  dist_mfma_kernel<<<N_TOT / BN, 256, 0, stream>>>(ze, cbh, cbsq, cand);
  rescore_kernel<<<NBLK_B, 256, 0, stream>>>(ze, cb, cbsq, cand, zq, idx_f, partial);
  finalize_kernel<<<1, 256, 0, stream>>>(partial, out_loss);
}

// Round 2
// 187.315 us; speedup vs baseline: 1.1221x; 1.0960x over previous
//
#include <hip/hip_runtime.h>

#define N_TOT 65536
#define C_DIM 128
#define K_CB  1024
#define BN 64
#define BT 64
#define NTILE (K_CB / BT)
#define NROW_B 4
#define NBLK_B (N_TOT / NROW_B)

typedef __attribute__((ext_vector_type(8))) short bf16x8;   // 8 bf16 = 4 VGPR
typedef __attribute__((ext_vector_type(4))) float f32x4;

__device__ __forceinline__ ushort f2bf_rne(float f) {
  unsigned u = __float_as_uint(f);
  return (ushort)((u + 0x7FFFu + ((u >> 16) & 1u)) >> 16);
}

#define GLDS16(src, dst)                                                       \
  __builtin_amdgcn_global_load_lds(                                            \
      (const __attribute__((address_space(1))) void*)(src),                    \
      (__attribute__((address_space(3))) void*)(dst), 16, 0, 0)

// ---------------------------------------------------------------------------
// cb_sq[k] = fl32( fp64 sum c^2 ) — one wave per code row. (frozen)
// ---------------------------------------------------------------------------
__global__ __launch_bounds__(256) void cbsq_kernel(const float* __restrict__ cb,
                                                   float* __restrict__ out) {
  int w = threadIdx.x >> 6, lane = threadIdx.x & 63;
  int r = blockIdx.x * 4 + w;
  float2 v = reinterpret_cast<const float2*>(cb + (size_t)r * C_DIM)[lane];
  double s = (double)v.x * (double)v.x + (double)v.y * (double)v.y;
#pragma unroll
  for (int off = 32; off >= 1; off >>= 1) s += __shfl_xor(s, off, 64);
  if (lane == 0) out[r] = (float)s;
}

// ---------------------------------------------------------------------------
// Codebook -> bf16 plane (RNE). (frozen)
// ---------------------------------------------------------------------------
__global__ __launch_bounds__(256) void cbconv_kernel(const float* __restrict__ cb,
                                                     ushort* __restrict__ cbh) {
  int gid = blockIdx.x * 256 + threadIdx.x;   // 0..32767 float4s
  float4 v = reinterpret_cast<const float4*>(cb)[gid];
  ushort4 h;
  h.x = f2bf_rne(v.x); h.y = f2bf_rne(v.y);
  h.z = f2bf_rne(v.z); h.w = f2bf_rne(v.w);
  reinterpret_cast<ushort4*>(cbh)[gid] = h;
}

// ---------------------------------------------------------------------------
// MFMA filter, R2: LDS-staged B path (request-rate fix).
//  - Old path read B frags per-lane from global: 16 scattered 64B segments
//    per dwordx4, x8 loads x16 tiles x4 waves, mh pairs duplicating — TA/L1
//    request-rate wall (MfmaUtil 7%, VALUBusy 18%, occupancy-insensitive).
//  - New: 16 KB B tile staged once per block via global_load_lds width=16
//    (contiguous 1 KB/instr, 4 instr/wave/tile), double-buffered, one
//    __syncthreads per tile (m97 structure). XOR-swizzle (row&7)<<4 applied
//    on the GLOBAL SOURCE side (gload_lds writes linearly, rule #21); frag
//    ds_read_b128 applies the same involution -> ~2-way banks (free).
//  - cbsq staged to LDS once (4 KB): kills 2 scattered global loads/tile.
//  - key' = (cbsq[k]+192) - 2*dot, packed (bits&~1023)|code, top-3 min/max
//    chain, pool stride 97, top-8 rescue: unchanged (R3/R7-verified).
// ---------------------------------------------------------------------------
__global__ __launch_bounds__(256, 3) void dist_mfma_kernel(
    const float* __restrict__ ze, const ushort* __restrict__ cbh,
    const float* __restrict__ cbsq, ushort* __restrict__ cand) {
  // [zh 16K | B0 16K | B1 16K | cbsq 4K] ; pool[24832] aliases zh+B0 (dead)
  __shared__ __align__(16) char smem[53248];
  ushort* zhS = reinterpret_cast<ushort*>(smem);          // [64][128] xor-swizzled
  unsigned* pool = reinterpret_cast<unsigned*>(smem);     // [64][97]
  char* const B0 = smem + 16384;
  char* const B1 = smem + 32768;
  float* const cbsqS = reinterpret_cast<float*>(smem + 49152);

  const int tid = threadIdx.x;
  const int w = tid >> 6, lane = tid & 63;
  const int mh = w & 1, nh = w >> 1;
  const int c16 = lane & 15, quad = lane >> 4;
  const int rowbase = blockIdx.x * BN;

  // Per-lane pre-swizzled source offsets for B staging (t-independent).
  // o = w*4096 + i*1024 + lane*16 ; row=o>>8 ; soff = row*256+(inrow^(row&7)<<4)
  int soff[4];
#pragma unroll
  for (int i = 0; i < 4; ++i) {
    int o = w * 4096 + i * 1024 + lane * 16;
    int row = o >> 8, inrow = o & 255;
    soff[i] = row * 256 + (inrow ^ ((row & 7) << 4));
  }
  const int stoff = w * 4096;   // wave-uniform LDS base within buffer

  // Issue tile-0 B stage first (in flight across z staging).
#pragma unroll
  for (int i = 0; i < 4; ++i)
    GLDS16((const char*)cbh + soff[i], B0 + stoff + i * 1024);

  // Stage z tile -> bf16 LDS (one time).
#pragma unroll
  for (int p = 0; p < 4; ++p) {
    int fid = p * 256 + tid;
    int row = fid >> 4, c8 = fid & 15;
    float4 a = reinterpret_cast<const float4*>(ze)[(size_t)(rowbase + row) * 32 + c8 * 2];
    float4 b = reinterpret_cast<const float4*>(ze)[(size_t)(rowbase + row) * 32 + c8 * 2 + 1];
    ushort h[8] = {f2bf_rne(a.x), f2bf_rne(a.y), f2bf_rne(a.z), f2bf_rne(a.w),
                   f2bf_rne(b.x), f2bf_rne(b.y), f2bf_rne(b.z), f2bf_rne(b.w)};
    *reinterpret_cast<uint4*>(&zhS[row * 128 + ((c8 ^ (row & 7)) * 8)]) =
        *reinterpret_cast<const uint4*>(h);
  }
  // cbsq -> LDS (1024 floats).
  reinterpret_cast<float4*>(cbsqS)[tid] = reinterpret_cast<const float4*>(cbsq)[tid];
  __syncthreads();   // drains vmcnt(0): tile-0 B stage complete too

  // Hoist A-frags: afrag[m2][ks], row = mh*32+m2*16+c16, k = ks*32+quad*8.
  const int xk = c16 & 7;
  bf16x8 afrag[2][4];
#pragma unroll
  for (int m2 = 0; m2 < 2; ++m2) {
    int r = (mh * 32 + m2 * 16 + c16) * 128;
#pragma unroll
    for (int ks = 0; ks < 4; ++ks)
      afrag[m2][ks] = *reinterpret_cast<const bf16x8*>(&zhS[r + ((ks * 4 + quad) ^ xk) * 8]);
  }

  unsigned t3[8][3];
#pragma unroll
  for (int s = 0; s < 8; ++s) { t3[s][0] = 0xFFFFFFFFu; t3[s][1] = 0xFFFFFFFFu; t3[s][2] = 0xFFFFFFFFu; }

  const int cbase = nh * 32 + c16;
  const char* cur = B0;
  char* nxt = B1;

  for (int t = 0; t < NTILE; ++t) {
    // Prefetch tile t+1 into the buffer consumed two tiles ago.
    if (t + 1 < NTILE) {
#pragma unroll
      for (int i = 0; i < 4; ++i)
        GLDS16((const char*)cbh + (size_t)(t + 1) * 16384 + soff[i], nxt + stoff + i * 1024);
    }

    // B frags from LDS (swizzled ds_read_b128): row r, inrow (ks*4+quad)^xk chunks.
    bf16x8 bf[2][4];
#pragma unroll
    for (int n2 = 0; n2 < 2; ++n2) {
      int rb = (nh * 32 + n2 * 16 + c16) * 256;
#pragma unroll
      for (int ks = 0; ks < 4; ++ks)
        bf[n2][ks] = *reinterpret_cast<const bf16x8*>(cur + rb + (((ks * 4 + quad) ^ xk) << 4));
    }

    f32x4 acc[2][2];
#pragma unroll
    for (int m2 = 0; m2 < 2; ++m2)
#pragma unroll
      for (int n2 = 0; n2 < 2; ++n2) acc[m2][n2] = (f32x4){0.f, 0.f, 0.f, 0.f};

#pragma unroll
    for (int ks = 0; ks < 4; ++ks)
#pragma unroll
      for (int m2 = 0; m2 < 2; ++m2)
#pragma unroll
        for (int n2 = 0; n2 < 2; ++n2)
          acc[m2][n2] = __builtin_amdgcn_mfma_f32_16x16x32_bf16(afrag[m2][ks], bf[n2][ks], acc[m2][n2], 0, 0, 0);

    // keys + packed top-3. D layout: col=lane&15, row=quad*4+reg (m89).
#pragma unroll
    for (int n2 = 0; n2 < 2; ++n2) {
      int code = t * BT + cbase + n2 * 16;
      float csb = cbsqS[t * BT + cbase + n2 * 16] + 192.0f;
#pragma unroll
      for (int m2 = 0; m2 < 2; ++m2)
#pragma unroll
        for (int reg = 0; reg < 4; ++reg) {
          float kf = fmaf(-2.f, acc[m2][n2][reg], csb);
          unsigned pk = (__float_as_uint(kf) & 0xFFFFFC00u) | (unsigned)code;
          int s = m2 * 4 + reg;
          unsigned c1 = min(t3[s][0], pk), h1 = max(t3[s][0], pk);
          unsigned c2 = min(t3[s][1], h1), h2 = max(t3[s][1], h1);
          unsigned c3 = min(t3[s][2], h2);
          t3[s][0] = c1; t3[s][1] = c2; t3[s][2] = c3;
        }
    }

    __syncthreads();   // one barrier/tile: drains stage (vmcnt) + frag reads
    char* tmp = const_cast<char*>(cur); cur = nxt; nxt = tmp;
  }

  // Pool: 32 (nh,c16) groups x top-3 = 96 packed keys per row.
#pragma unroll
  for (int s = 0; s < 8; ++s) {
    int row = mh * 32 + (s >> 2) * 16 + quad * 4 + (s & 3);
    int col = (nh * 16 + c16) * 3;
    pool[row * 97 + col] = t3[s][0];
    pool[row * 97 + col + 1] = t3[s][1];
    pool[row * 97 + col + 2] = t3[s][2];
  }
  __syncthreads();
  if (tid < BN) {
    unsigned k[8];
#pragma unroll
    for (int q = 0; q < 8; ++q) k[q] = 0xFFFFFFFFu;
    for (int p = 0; p < 96; ++p) {
      unsigned v = pool[tid * 97 + p];
      if (v < k[7]) {
        k[7] = v;
#pragma unroll
        for (int q = 7; q > 0; --q)
          if (k[q] < k[q - 1]) { unsigned tk = k[q]; k[q] = k[q - 1]; k[q - 1] = tk; }
      }
    }
    uint4 cw;
    cw.x = (k[0] & 1023u) | ((k[1] & 1023u) << 16);
    cw.y = (k[2] & 1023u) | ((k[3] & 1023u) << 16);
    cw.z = (k[4] & 1023u) | ((k[5] & 1023u) << 16);
    cw.w = (k[6] & 1023u) | ((k[7] & 1023u) << 16);
    reinterpret_cast<uint4*>(cand)[rowbase + tid] = cw;
  }
}

// ---------------------------------------------------------------------------
// Rescore (R3/R7-verified, UNTOUCHED): np fp32 key replication
//   key = fl32( fl32( zs - fl32(2*cross_fp64) ) + cb_sq32 ), tie -> low idx.
// ---------------------------------------------------------------------------
__global__ __launch_bounds__(256) void rescore_kernel(
    const float* __restrict__ ze, const float* __restrict__ cb,
    const float* __restrict__ cbsq, const ushort* __restrict__ cand,
    float* __restrict__ zq, float* __restrict__ idx_f,
    double* __restrict__ partial) {
  int w = threadIdx.x >> 6, lane = threadIdx.x & 63;
  int row = blockIdx.x * NROW_B + w;
  int g = lane >> 3, e = lane & 7;
  int myc = cand[(size_t)row * 8 + g];

  float2 z2 = reinterpret_cast<const float2*>(ze)[(size_t)row * 64 + lane];
  double zsum = (double)z2.x * (double)z2.x + (double)z2.y * (double)z2.y;
#pragma unroll
  for (int off = 32; off >= 1; off >>= 1) zsum += __shfl_xor(zsum, off, 64);
  float zs = (float)zsum;

  const float4* zrow4 = reinterpret_cast<const float4*>(ze + (size_t)row * C_DIM);
  const float4* crow4 = reinterpret_cast<const float4*>(cb + (size_t)myc * C_DIM);
  double p = 0.0;
#pragma unroll
  for (int q = 0; q < 4; ++q) {
    float4 zz = zrow4[e * 4 + q];
    float4 cc = crow4[e * 4 + q];
    p += (double)zz.x * (double)cc.x + (double)zz.y * (double)cc.y +
         (double)zz.z * (double)cc.z + (double)zz.w * (double)cc.w;
  }
  p += __shfl_xor(p, 1, 64);
  p += __shfl_xor(p, 2, 64);
  p += __shfl_xor(p, 4, 64);

  float tt = (float)(2.0 * p);
  float u = zs - tt;
  float d = u + cbsq[myc];

  float best = 3.4e38f;
  int bidx = K_CB + 1;
#pragma unroll
  for (int gg = 0; gg < 8; ++gg) {
    float dg = __shfl(d, gg * 8, 64);
    int ig = __shfl(myc, gg * 8, 64);
    if (dg < best || (dg == best && ig < bidx)) { best = dg; bidx = ig; }
  }

  float2 c2 = reinterpret_cast<const float2*>(cb)[(size_t)bidx * 64 + lane];
  reinterpret_cast<float2*>(zq)[(size_t)row * 64 + lane] = c2;

  double dx = (double)z2.x - (double)c2.x;
  double dy = (double)z2.y - (double)c2.y;
  double l = dx * dx + dy * dy;
#pragma unroll
  for (int off = 32; off >= 1; off >>= 1) l += __shfl_xor(l, off, 64);

  __shared__ double sh[NROW_B];
  if (lane == 0) { idx_f[row] = (float)bidx; sh[w] = l; }
  __syncthreads();
  if (threadIdx.x == 0) partial[blockIdx.x] = sh[0] + sh[1] + sh[2] + sh[3];
}

__global__ __launch_bounds__(256) void finalize_kernel(
    const double* __restrict__ partial, float* __restrict__ out_loss) {
  double s = 0.0;
  for (int i = threadIdx.x; i < NBLK_B; i += 256) s += partial[i];
#pragma unroll
  for (int off = 32; off >= 1; off >>= 1) s += __shfl_down(s, off, 64);
  __shared__ double sh[4];
  int wv = threadIdx.x >> 6, lane = threadIdx.x & 63;
  if (lane == 0) sh[wv] = s;
  __syncthreads();
  if (threadIdx.x == 0) {
    double tot = sh[0] + sh[1] + sh[2] + sh[3];
    double mse = tot / (double)((size_t)N_TOT * C_DIM);
    *out_loss = (float)(1.75 * mse);  // 0.75*q_latent + e_latent, both == mse
  }
}

// ---------------------------------------------------------------------------
extern "C" void kernel_launch(void* const* d_in, const int* in_sizes, int n_in,
                              void* d_out, int out_size, void* d_ws, size_t ws_size,
                              hipStream_t stream) {
  const float* ze = (const float*)d_in[0];
  const float* cb = (const float*)d_in[1];

  float* out = (float*)d_out;
  float* zq = out;                                   // [N*C]
  float* out_loss = out + (size_t)N_TOT * C_DIM;     // [1]
  float* idx_f = out_loss + 1;                       // [N]

  float* cbsq = (float*)d_ws;                             // 4 KB @0
  ushort* cbh = (ushort*)((char*)d_ws + 8192);            // 256 KB
  ushort* cand = (ushort*)((char*)d_ws + 270336);         // 1 MB
  double* partial = (double*)((char*)d_ws + 1318912);     // 128 KB

  cbsq_kernel<<<K_CB / 4, 256, 0, stream>>>(cb, cbsq);
  cbconv_kernel<<<K_CB * C_DIM / 4 / 256, 256, 0, stream>>>(cb, cbh);
  dist_mfma_kernel<<<N_TOT / BN, 256, 0, stream>>>(ze, cbh, cbsq, cand);
  rescore_kernel<<<NBLK_B, 256, 0, stream>>>(ze, cb, cbsq, cand, zq, idx_f, partial);
  finalize_kernel<<<1, 256, 0, stream>>>(partial, out_loss);
}